// Round 1
// baseline (436.426 us; speedup 1.0000x reference)
//
#include <hip/hip_runtime.h>
#include <hip/hip_bf16.h>

typedef _Float16 f16x8 __attribute__((ext_vector_type(8)));
typedef float f32x4 __attribute__((ext_vector_type(4)));

// B=16, C=512, HEAD=8, D=64, N=1024 (W=H=32)

__device__ inline void gll16(const void* g, void* l) {
  __builtin_amdgcn_global_load_lds(
      (const __attribute__((address_space(1))) void*)g,
      (__attribute__((address_space(3))) void*)l, 16, 0, 0);
}

// ---------------- prep: Wall f16 + pos f16 ----------------
__global__ __launch_bounds__(256) void prep_kernel(
    const float* __restrict__ Wq, const float* __restrict__ Wk, const float* __restrict__ Wv,
    const float* __restrict__ rel_h, const float* __restrict__ rel_w,
    _Float16* __restrict__ Wall, _Float16* __restrict__ post) {
  int idx = blockIdx.x * 256 + threadIdx.x;
  if (idx < 1536 * 512) {
    int o = idx >> 9;
    float wv;
    if (o < 512) wv = Wq[idx];
    else if (o < 1024) wv = Wk[idx - 512 * 512];
    else wv = Wv[idx - 1024 * 512];
    Wall[idx] = (_Float16)wv;
  } else {
    int p = idx - 1536 * 512;            // [0, 8*1024*64)
    int h = p >> 16;
    int rem = p & 65535;
    int n = rem >> 6;
    int d = rem & 63;
    // pos[h][d][n] = rel_h[h,d,n%32] + rel_w[h,d,n/32]; store as post[h][n][d]
    float v = rel_h[(h * 64 + d) * 32 + (n & 31)] + rel_w[(h * 64 + d) * 32 + (n >> 5)];
    post[p] = (_Float16)v;
  }
}

// ---------------- transpose: x[B,C,N] f32 -> Xt[B*N, C] f16 ----------------
__global__ __launch_bounds__(256) void transpose_kernel(
    const float* __restrict__ x, _Float16* __restrict__ Xt) {
  __shared__ float tl[64][65];
  int bid = blockIdx.x;
  int b = bid >> 7;
  int rem = bid & 127;
  int c0 = (rem >> 4) * 64;
  int n0 = (rem & 15) * 64;
  int t = threadIdx.x;
#pragma unroll
  for (int p = 0; p < 16; ++p) {
    int idx = p * 256 + t;
    int i = idx >> 6, j = idx & 63;
    tl[i][j] = x[((size_t)b * 512 + c0 + i) * 1024 + n0 + j];
  }
  __syncthreads();
#pragma unroll
  for (int p = 0; p < 16; ++p) {
    int idx = p * 256 + t;
    int j = idx >> 6, i = idx & 63;
    Xt[((size_t)b * 1024 + n0 + j) * 512 + c0 + i] = (_Float16)tl[i][j];
  }
}

// ---------------- QKV projection GEMM ----------------
// Y[o, j] = sum_c Wall[o,c] * Xt[j,c] + bias(o);  o in [0,1536), j = b*1024+n
// writes qt[b][h][n][d], kt[b][h][n][d], v[b][h][d][n]  (f16)
__global__ __launch_bounds__(256) void qkv_gemm(
    const _Float16* __restrict__ Wall, const _Float16* __restrict__ Xt,
    const float* __restrict__ bq, const float* __restrict__ bk, const float* __restrict__ bv,
    _Float16* __restrict__ qt, _Float16* __restrict__ kt, _Float16* __restrict__ vv) {
  __shared__ _Float16 At[128 * 64];
  __shared__ _Float16 Bt[128 * 64];
  int bid = blockIdx.x;
  int mb = bid >> 7, nb = bid & 127;
  int o0 = mb * 128, j0 = nb * 128;
  int t = threadIdx.x;
  int w = t >> 6, l = t & 63, lg = l >> 4, lc = l & 15;
  int wm = w >> 1, wn = w & 1;
  f32x4 acc[4][4];
#pragma unroll
  for (int a = 0; a < 4; ++a)
#pragma unroll
    for (int bb = 0; bb < 4; ++bb) acc[a][bb] = (f32x4){0.f, 0.f, 0.f, 0.f};

  for (int k0 = 0; k0 < 512; k0 += 64) {
    __syncthreads();
#pragma unroll
    for (int p = 0; p < 4; ++p) {
      int li = p * 256 + t;            // 16B chunk index
      int row = li >> 3;               // tile row
      int colb = (li & 7) << 4;        // linear byte col in row
      int scol = (colb ^ ((row & 7) << 4)) >> 1;  // inverse-swizzled f16 col
      gll16(Wall + (size_t)(o0 + row) * 512 + k0 + scol, At + (size_t)li * 8);
      gll16(Xt + (size_t)(j0 + row) * 512 + k0 + scol, Bt + (size_t)li * 8);
    }
    __syncthreads();
#pragma unroll
    for (int kf = 0; kf < 2; ++kf) {
      int kbyte = kf * 64 + lg * 16;
      f16x8 af[4], bf[4];
#pragma unroll
      for (int mi = 0; mi < 4; ++mi) {
        int row = wm * 64 + mi * 16 + lc;
        af[mi] = *(const f16x8*)((const char*)At + row * 128 + (kbyte ^ ((row & 7) << 4)));
      }
#pragma unroll
      for (int ni = 0; ni < 4; ++ni) {
        int row = wn * 64 + ni * 16 + lc;
        bf[ni] = *(const f16x8*)((const char*)Bt + row * 128 + (kbyte ^ ((row & 7) << 4)));
      }
#pragma unroll
      for (int mi = 0; mi < 4; ++mi)
#pragma unroll
        for (int ni = 0; ni < 4; ++ni)
          acc[mi][ni] = __builtin_amdgcn_mfma_f32_16x16x32_f16(af[mi], bf[ni], acc[mi][ni], 0, 0, 0);
    }
  }

  int mode = mb >> 2;  // 0=q, 1=k, 2=v (tile-uniform: 512/128=4 M-tiles per matrix)
  const float* bias = (mode == 0) ? bq : ((mode == 1) ? bk : bv);
#pragma unroll
  for (int mi = 0; mi < 4; ++mi) {
    int obase = o0 + wm * 64 + mi * 16 + 4 * lg - mode * 512;
#pragma unroll
    for (int ni = 0; ni < 4; ++ni) {
      int j = j0 + wn * 64 + ni * 16 + lc;
      int b = j >> 10, n = j & 1023;
#pragma unroll
      for (int r = 0; r < 4; ++r) {
        int op = obase + r;                 // channel within matrix [0,512)
        float y = acc[mi][ni][r] + bias[op];
        int h = op >> 6, d = op & 63;
        if (mode < 2) {
          _Float16* dst = (mode == 0) ? qt : kt;
          dst[(((size_t)b * 8 + h) * 1024 + n) * 64 + d] = (_Float16)y;
        } else {
          vv[(((size_t)b * 8 + h) * 64 + d) * 1024 + n] = (_Float16)y;
        }
      }
    }
  }
}

// ---------------- fused flash attention + residual ----------------
// logits[n,m] = sum_d q[n,d]k[m,d] + sum_d pos[n,d]q[m,d]   (K-ext = 128)
// out[b, h*64+d, n] = sum_m softmax_m(logits)[n,m] * v[d,m] + x[b, h*64+d, n]
__global__ __launch_bounds__(256) void attn_kernel(
    const _Float16* __restrict__ qt, const _Float16* __restrict__ kt,
    const _Float16* __restrict__ vv, const _Float16* __restrict__ post,
    const float* __restrict__ x, float* __restrict__ out) {
  __shared__ _Float16 p_lds[4][1024];  // per-wave 16x64 f16, XOR-swizzled
  int bid = blockIdx.x;
  int bh = bid >> 4, qb = bid & 15;
  int b = bh >> 3, h = bh & 7;
  int t = threadIdx.x, w = t >> 6, l = t & 63, lg = l >> 4, lc = l & 15;
  const _Float16* qbh = qt + (size_t)bh * 65536;
  const _Float16* kbh = kt + (size_t)bh * 65536;
  const _Float16* vbh = vv + (size_t)bh * 65536;
  const _Float16* ph = post + (size_t)h * 65536;
  int n0 = qb * 64 + w * 16;  // wave's 16 query rows

  f16x8 aq[4];  // A-frags over K-ext=128: [q | pos]
#pragma unroll
  for (int kf = 0; kf < 4; ++kf) {
    int kk = kf * 32 + lg * 8;
    const _Float16* src = (kk < 64) ? (qbh + (size_t)(n0 + lc) * 64 + kk)
                                    : (ph + (size_t)(n0 + lc) * 64 + (kk - 64));
    aq[kf] = *(const f16x8*)src;
  }

  float m_r[4], l_r[4];
  f32x4 oacc[4];
#pragma unroll
  for (int r = 0; r < 4; ++r) { m_r[r] = -1e30f; l_r[r] = 0.f; }
#pragma unroll
  for (int dt = 0; dt < 4; ++dt) oacc[dt] = (f32x4){0.f, 0.f, 0.f, 0.f};
  char* pl = (char*)p_lds[w];

  for (int mt = 0; mt < 16; ++mt) {
    int m0 = mt * 64;
    f32x4 sS[4];
#pragma unroll
    for (int ms = 0; ms < 4; ++ms) {
      int mc = m0 + ms * 16 + lc;
      f32x4 s = (f32x4){0.f, 0.f, 0.f, 0.f};
#pragma unroll
      for (int kf = 0; kf < 4; ++kf) {
        int kk = kf * 32 + lg * 8;
        const _Float16* src = (kk < 64) ? (kbh + (size_t)mc * 64 + kk)
                                        : (qbh + (size_t)mc * 64 + (kk - 64));
        f16x8 bk = *(const f16x8*)src;
        s = __builtin_amdgcn_mfma_f32_16x16x32_f16(aq[kf], bk, s, 0, 0, 0);
      }
      sS[ms] = s;
    }
    // online softmax over this 64-wide m-tile; row r of lane = n0 + 4*lg + r
    float rmax[4], mnew[4], scale[4], rsum[4];
#pragma unroll
    for (int r = 0; r < 4; ++r)
      rmax[r] = fmaxf(fmaxf(sS[0][r], sS[1][r]), fmaxf(sS[2][r], sS[3][r]));
#pragma unroll
    for (int dd = 1; dd < 16; dd <<= 1)
#pragma unroll
      for (int r = 0; r < 4; ++r)
        rmax[r] = fmaxf(rmax[r], __shfl_xor(rmax[r], dd));
#pragma unroll
    for (int r = 0; r < 4; ++r) {
      mnew[r] = fmaxf(m_r[r], rmax[r]);
      scale[r] = __expf(m_r[r] - mnew[r]);
      rsum[r] = 0.f;
    }
    __syncthreads();  // previous iter's P reads done before overwrite
#pragma unroll
    for (int ms = 0; ms < 4; ++ms)
#pragma unroll
      for (int r = 0; r < 4; ++r) {
        float p = __expf(sS[ms][r] - mnew[r]);
        rsum[r] += p;
        int row = 4 * lg + r;
        int colb = (ms * 16 + lc) << 1;
        *(_Float16*)(pl + row * 128 + (colb ^ ((row & 7) << 4))) = (_Float16)p;
      }
    __syncthreads();  // P visible
#pragma unroll
    for (int dd = 1; dd < 16; dd <<= 1)
#pragma unroll
      for (int r = 0; r < 4; ++r)
        rsum[r] += __shfl_xor(rsum[r], dd);
#pragma unroll
    for (int r = 0; r < 4; ++r) {
      l_r[r] = l_r[r] * scale[r] + rsum[r];
      m_r[r] = mnew[r];
    }
#pragma unroll
    for (int dt = 0; dt < 4; ++dt)
#pragma unroll
      for (int r = 0; r < 4; ++r)
        oacc[dt][r] *= scale[r];
    // PV: O[n,d] += P[n,m] * v[d,m]
#pragma unroll
    for (int ks = 0; ks < 2; ++ks) {
      int kbyte = ks * 64 + lg * 16;
      f16x8 pa = *(const f16x8*)(pl + lc * 128 + (kbyte ^ ((lc & 7) << 4)));
#pragma unroll
      for (int dt = 0; dt < 4; ++dt) {
        const _Float16* vsrc = vbh + (size_t)(dt * 16 + lc) * 1024 + m0 + ks * 32 + lg * 8;
        f16x8 bv = *(const f16x8*)vsrc;
        oacc[dt] = __builtin_amdgcn_mfma_f32_16x16x32_f16(pa, bv, oacc[dt], 0, 0, 0);
      }
    }
  }
  // epilogue: divide by l, add residual, store float4 (4 consecutive n)
#pragma unroll
  for (int dt = 0; dt < 4; ++dt) {
    int dd = dt * 16 + lc;
    int c = h * 64 + dd;
    size_t base = ((size_t)b * 512 + c) * 1024 + n0 + 4 * lg;
    float4 xr = *(const float4*)(x + base);
    float4 o;
    o.x = oacc[dt][0] / l_r[0] + xr.x;
    o.y = oacc[dt][1] / l_r[1] + xr.y;
    o.z = oacc[dt][2] / l_r[2] + xr.z;
    o.w = oacc[dt][3] / l_r[3] + xr.w;
    *(float4*)(out + base) = o;
  }
}

extern "C" void kernel_launch(void* const* d_in, const int* in_sizes, int n_in,
                              void* d_out, int out_size, void* d_ws, size_t ws_size,
                              hipStream_t stream) {
  (void)in_sizes; (void)n_in; (void)out_size; (void)ws_size;
  const float* x = (const float*)d_in[0];
  const float* Wq = (const float*)d_in[1];
  const float* bq = (const float*)d_in[2];
  const float* Wk = (const float*)d_in[3];
  const float* bk = (const float*)d_in[4];
  const float* Wv = (const float*)d_in[5];
  const float* bv = (const float*)d_in[6];
  const float* rel_h = (const float*)d_in[7];
  const float* rel_w = (const float*)d_in[8];
  float* out = (float*)d_out;

  char* ws = (char*)d_ws;
  _Float16* Xt   = (_Float16*)(ws);                          // 16 MiB
  _Float16* Wall = (_Float16*)(ws + (16u << 20));            // 1.5 MiB
  _Float16* post = (_Float16*)(ws + (18u << 20));            // 1 MiB
  _Float16* qtw  = (_Float16*)(ws + (19u << 20));            // 16 MiB
  _Float16* ktw  = (_Float16*)(ws + (35u << 20));            // 16 MiB
  _Float16* vw   = (_Float16*)(ws + (51u << 20));            // 16 MiB

  hipLaunchKernelGGL(prep_kernel, dim3(5120), dim3(256), 0, stream,
                     Wq, Wk, Wv, rel_h, rel_w, Wall, post);
  hipLaunchKernelGGL(transpose_kernel, dim3(2048), dim3(256), 0, stream, x, Xt);
  hipLaunchKernelGGL(qkv_gemm, dim3(1536), dim3(256), 0, stream,
                     Wall, Xt, bq, bk, bv, qtw, ktw, vw);
  hipLaunchKernelGGL(attn_kernel, dim3(2048), dim3(256), 0, stream,
                     qtw, ktw, vw, post, x, out);
}

// Round 2
// 199.369 us; speedup vs baseline: 2.1890x; 2.1890x over previous
//
#include <hip/hip_runtime.h>
#include <hip/hip_bf16.h>

typedef _Float16 f16x8 __attribute__((ext_vector_type(8)));
typedef float f32x4 __attribute__((ext_vector_type(4)));

// B=16, C=512, HEAD=8, D=64, N=1024 (W=H=32)

__device__ inline void gll16(const void* g, void* l) {
  __builtin_amdgcn_global_load_lds(
      (const __attribute__((address_space(1))) void*)g,
      (__attribute__((address_space(3))) void*)l, 16, 0, 0);
}

// ---------------- prep: Wall f16 + pos f16 ----------------
__global__ __launch_bounds__(256) void prep_kernel(
    const float* __restrict__ Wq, const float* __restrict__ Wk, const float* __restrict__ Wv,
    const float* __restrict__ rel_h, const float* __restrict__ rel_w,
    _Float16* __restrict__ Wall, _Float16* __restrict__ post) {
  int idx = blockIdx.x * 256 + threadIdx.x;
  if (idx < 1536 * 512) {
    int o = idx >> 9;
    float wv;
    if (o < 512) wv = Wq[idx];
    else if (o < 1024) wv = Wk[idx - 512 * 512];
    else wv = Wv[idx - 1024 * 512];
    Wall[idx] = (_Float16)wv;
  } else {
    int p = idx - 1536 * 512;            // [0, 8*1024*64)
    int h = p >> 16;
    int rem = p & 65535;
    int n = rem >> 6;
    int d = rem & 63;
    float v = rel_h[(h * 64 + d) * 32 + (n & 31)] + rel_w[(h * 64 + d) * 32 + (n >> 5)];
    post[p] = (_Float16)v;
  }
}

// ---------------- transpose: x[B,C,N] f32 -> Xt[B*N, C] f16 ----------------
__global__ __launch_bounds__(256) void transpose_kernel(
    const float* __restrict__ x, _Float16* __restrict__ Xt) {
  __shared__ float tl[64][65];
  int bid = blockIdx.x;
  int b = bid >> 7;
  int rem = bid & 127;
  int c0 = (rem >> 4) * 64;
  int n0 = (rem & 15) * 64;
  int t = threadIdx.x;
#pragma unroll
  for (int p = 0; p < 16; ++p) {
    int idx = p * 256 + t;
    int i = idx >> 6, j = idx & 63;
    tl[i][j] = x[((size_t)b * 512 + c0 + i) * 1024 + n0 + j];
  }
  __syncthreads();
#pragma unroll
  for (int p = 0; p < 16; ++p) {
    int idx = p * 256 + t;
    int j = idx >> 6, i = idx & 63;
    Xt[((size_t)b * 1024 + n0 + j) * 512 + c0 + i] = (_Float16)tl[i][j];
  }
}

// ---------------- QKV projection GEMM ----------------
// Y[o, j] = sum_c Wall[o,c] * Xt[j,c] + bias(o);  o in [0,1536), j = b*1024+n
// writes Kext[b][h][n][0:64]=k, [64:128]=q ; v[b][h][d][n]  (f16)
__global__ __launch_bounds__(256) void qkv_gemm(
    const _Float16* __restrict__ Wall, const _Float16* __restrict__ Xt,
    const float* __restrict__ bq, const float* __restrict__ bk, const float* __restrict__ bv,
    _Float16* __restrict__ kext, _Float16* __restrict__ vv) {
  __shared__ _Float16 At[128 * 64];
  __shared__ _Float16 Bt[128 * 64];
  int bid = blockIdx.x;
  int mb = bid >> 7, nb = bid & 127;
  int o0 = mb * 128, j0 = nb * 128;
  int t = threadIdx.x;
  int w = t >> 6, l = t & 63, lg = l >> 4, lc = l & 15;
  int wm = w >> 1, wn = w & 1;
  f32x4 acc[4][4];
#pragma unroll
  for (int a = 0; a < 4; ++a)
#pragma unroll
    for (int bb = 0; bb < 4; ++bb) acc[a][bb] = (f32x4){0.f, 0.f, 0.f, 0.f};

  for (int k0 = 0; k0 < 512; k0 += 64) {
    __syncthreads();
#pragma unroll
    for (int p = 0; p < 4; ++p) {
      int li = p * 256 + t;            // 16B chunk index
      int row = li >> 3;               // tile row
      int colb = (li & 7) << 4;        // linear byte col in row
      int scol = (colb ^ ((row & 7) << 4)) >> 1;  // inverse-swizzled f16 col
      gll16(Wall + (size_t)(o0 + row) * 512 + k0 + scol, At + (size_t)li * 8);
      gll16(Xt + (size_t)(j0 + row) * 512 + k0 + scol, Bt + (size_t)li * 8);
    }
    __syncthreads();
#pragma unroll
    for (int kf = 0; kf < 2; ++kf) {
      int kbyte = kf * 64 + lg * 16;
      f16x8 af[4], bf[4];
#pragma unroll
      for (int mi = 0; mi < 4; ++mi) {
        int row = wm * 64 + mi * 16 + lc;
        af[mi] = *(const f16x8*)((const char*)At + row * 128 + (kbyte ^ ((row & 7) << 4)));
      }
#pragma unroll
      for (int ni = 0; ni < 4; ++ni) {
        int row = wn * 64 + ni * 16 + lc;
        bf[ni] = *(const f16x8*)((const char*)Bt + row * 128 + (kbyte ^ ((row & 7) << 4)));
      }
#pragma unroll
      for (int mi = 0; mi < 4; ++mi)
#pragma unroll
        for (int ni = 0; ni < 4; ++ni)
          acc[mi][ni] = __builtin_amdgcn_mfma_f32_16x16x32_f16(af[mi], bf[ni], acc[mi][ni], 0, 0, 0);
    }
  }

  int mode = mb >> 2;  // 0=q, 1=k, 2=v
  const float* bias = (mode == 0) ? bq : ((mode == 1) ? bk : bv);
#pragma unroll
  for (int mi = 0; mi < 4; ++mi) {
    int obase = o0 + wm * 64 + mi * 16 + 4 * lg - mode * 512;
#pragma unroll
    for (int ni = 0; ni < 4; ++ni) {
      int j = j0 + wn * 64 + ni * 16 + lc;
      int b = j >> 10, n = j & 1023;
#pragma unroll
      for (int r = 0; r < 4; ++r) {
        int op = obase + r;                 // channel within matrix [0,512)
        float y = acc[mi][ni][r] + bias[op];
        int h = op >> 6, d = op & 63;
        if (mode < 2) {
          size_t off = ((((size_t)b * 8 + h) * 1024 + n) * 128) + d + (mode == 0 ? 64 : 0);
          kext[off] = (_Float16)y;
        } else {
          vv[(((size_t)b * 8 + h) * 64 + d) * 1024 + n] = (_Float16)y;
        }
      }
    }
  }
}

// ---------------- fused flash attention + residual ----------------
// logits[n,m] = sum_{kk<128} Aext[n,kk] * Kext[m,kk], Aext=[q_n|pos_n], Kext=[k_m|q_m]
// out[b, h*64+d, n] = sum_m softmax_m(logits)[n,m] * v[d,m] + x[b, h*64+d, n]
__global__ __launch_bounds__(256, 2) void attn_kernel(
    const _Float16* __restrict__ kext, const _Float16* __restrict__ vv,
    const _Float16* __restrict__ post,
    const float* __restrict__ x, float* __restrict__ out) {
  __shared__ _Float16 Ke[2][8192];   // 64 x 128 f16, rows 256B, XOR-swizzled 16B chunks
  __shared__ _Float16 Vs[2][4096];   // 64 x 64 f16, rows 128B, XOR-swizzled
  __shared__ _Float16 Pl[4][2048];   // per-wave 32 x 64 f16, rows 128B, XOR-swizzled
  int bid = blockIdx.x;
  int bh = bid & 127, qb = bid >> 7;   // same-bh blocks share XCD (bid%8 == bh%8)
  int b = bh >> 3, h = bh & 7;
  int t = threadIdx.x, w = t >> 6, l = t & 63, lg = l >> 4, lc = l & 15;
  const _Float16* keg = kext + (size_t)bh * (1024 * 128);
  const _Float16* vbh = vv + (size_t)bh * 65536;
  const _Float16* ph = post + (size_t)h * 65536;
  int n0w = qb * 128 + w * 32;

  // A-frags over K-ext=128: [q | pos], 2 row-frags of 16 rows each
  f16x8 aq[2][4];
#pragma unroll
  for (int rf = 0; rf < 2; ++rf)
#pragma unroll
    for (int kf = 0; kf < 4; ++kf) {
      int kk = kf * 32 + lg * 8;
      int n = n0w + rf * 16 + lc;
      const _Float16* src = (kf < 2) ? (keg + (size_t)n * 128 + 64 + kk)
                                     : (ph + (size_t)n * 64 + (kk - 64));
      aq[rf][kf] = *(const f16x8*)src;
    }

  float m_r[2][4], l_r[2][4];
  f32x4 oacc[2][4];
#pragma unroll
  for (int rf = 0; rf < 2; ++rf)
#pragma unroll
    for (int r = 0; r < 4; ++r) { m_r[rf][r] = -1e30f; l_r[rf][r] = 0.f; }
#pragma unroll
  for (int rf = 0; rf < 2; ++rf)
#pragma unroll
    for (int dt = 0; dt < 4; ++dt) oacc[rf][dt] = (f32x4){0.f, 0.f, 0.f, 0.f};

  // stage tile mt into buffer buf
  auto stage = [&](int buf, int mt) {
    int m0 = mt * 64;
#pragma unroll
    for (int p = 0; p < 4; ++p) {
      int li = p * 256 + t;
      int r = li >> 4, c = li & 15;
      int sc = c ^ (r & 7);
      gll16(keg + (size_t)(m0 + r) * 128 + sc * 8, (char*)Ke[buf] + li * 16);
    }
#pragma unroll
    for (int p = 0; p < 2; ++p) {
      int li = p * 256 + t;
      int r = li >> 3, c = li & 7;
      int sc = c ^ (r & 7);
      gll16(vbh + (size_t)r * 1024 + m0 + sc * 8, (char*)Vs[buf] + li * 16);
    }
  };

  stage(0, 0);
  __syncthreads();
  int buf = 0;
  char* pw = (char*)Pl[w];

  for (int mt = 0; mt < 16; ++mt) {
    if (mt + 1 < 16) stage(buf ^ 1, mt + 1);
    const char* keb = (const char*)Ke[buf];
    const char* vsb = (const char*)Vs[buf];

    // QK^T (K-ext 128)
    f32x4 sS[2][4];
#pragma unroll
    for (int rf = 0; rf < 2; ++rf)
#pragma unroll
      for (int ms = 0; ms < 4; ++ms) sS[rf][ms] = (f32x4){0.f, 0.f, 0.f, 0.f};
#pragma unroll
    for (int ms = 0; ms < 4; ++ms) {
      int mr = ms * 16 + lc;
      const char* rowp = keb + mr * 256;
      f16x8 bkf[4];
#pragma unroll
      for (int kf = 0; kf < 4; ++kf) {
        int ch = (kf * 4 + lg) ^ (mr & 7);
        bkf[kf] = *(const f16x8*)(rowp + (ch << 4));
      }
#pragma unroll
      for (int rf = 0; rf < 2; ++rf)
#pragma unroll
        for (int kf = 0; kf < 4; ++kf)
          sS[rf][ms] = __builtin_amdgcn_mfma_f32_16x16x32_f16(aq[rf][kf], bkf[kf], sS[rf][ms], 0, 0, 0);
    }

    // online softmax per 16-row frag; lane's rows: rf*16 + 4*lg + r
    float scale[2][4];
#pragma unroll
    for (int rf = 0; rf < 2; ++rf) {
      float rmax[4], rsum[4];
#pragma unroll
      for (int r = 0; r < 4; ++r)
        rmax[r] = fmaxf(fmaxf(sS[rf][0][r], sS[rf][1][r]), fmaxf(sS[rf][2][r], sS[rf][3][r]));
#pragma unroll
      for (int dd = 1; dd < 16; dd <<= 1)
#pragma unroll
        for (int r = 0; r < 4; ++r)
          rmax[r] = fmaxf(rmax[r], __shfl_xor(rmax[r], dd));
#pragma unroll
      for (int r = 0; r < 4; ++r) {
        float mnew = fmaxf(m_r[rf][r], rmax[r]);
        scale[rf][r] = __expf(m_r[rf][r] - mnew);
        m_r[rf][r] = mnew;
        rsum[r] = 0.f;
      }
#pragma unroll
      for (int ms = 0; ms < 4; ++ms)
#pragma unroll
        for (int r = 0; r < 4; ++r) {
          float p = __expf(sS[rf][ms][r] - m_r[rf][r]);
          rsum[r] += p;
          int pr = rf * 16 + 4 * lg + r;
          int col = ms * 16 + lc;
          int ch = (col >> 3) ^ (pr & 7);
          *(_Float16*)(pw + pr * 128 + (ch << 4) + ((col & 7) << 1)) = (_Float16)p;
        }
#pragma unroll
      for (int dd = 1; dd < 16; dd <<= 1)
#pragma unroll
        for (int r = 0; r < 4; ++r)
          rsum[r] += __shfl_xor(rsum[r], dd);
#pragma unroll
      for (int r = 0; r < 4; ++r)
        l_r[rf][r] = l_r[rf][r] * scale[rf][r] + rsum[r];
    }
#pragma unroll
    for (int rf = 0; rf < 2; ++rf)
#pragma unroll
      for (int dt = 0; dt < 4; ++dt)
#pragma unroll
        for (int r = 0; r < 4; ++r)
          oacc[rf][dt][r] *= scale[rf][r];

    // PV: O[n,d] += P[n,m] * v[d,m]
    f16x8 bvv[2][4];
#pragma unroll
    for (int ks = 0; ks < 2; ++ks)
#pragma unroll
      for (int dt = 0; dt < 4; ++dt) {
        int vr = dt * 16 + lc;
        int ch = (ks * 4 + lg) ^ (vr & 7);
        bvv[ks][dt] = *(const f16x8*)(vsb + vr * 128 + (ch << 4));
      }
#pragma unroll
    for (int rf = 0; rf < 2; ++rf) {
      int pr = rf * 16 + lc;
#pragma unroll
      for (int ks = 0; ks < 2; ++ks) {
        int ch = (ks * 4 + lg) ^ (pr & 7);
        f16x8 pa = *(const f16x8*)(pw + pr * 128 + (ch << 4));
#pragma unroll
        for (int dt = 0; dt < 4; ++dt)
          oacc[rf][dt] = __builtin_amdgcn_mfma_f32_16x16x32_f16(pa, bvv[ks][dt], oacc[rf][dt], 0, 0, 0);
      }
    }
    __syncthreads();  // staged loads drained (implicit vmcnt(0)) + all waves done with buf
    buf ^= 1;
  }

  // epilogue: divide by l, add residual, store float4 (4 consecutive n)
#pragma unroll
  for (int rf = 0; rf < 2; ++rf) {
    float inv[4];
#pragma unroll
    for (int r = 0; r < 4; ++r) inv[r] = 1.0f / l_r[rf][r];
#pragma unroll
    for (int dt = 0; dt < 4; ++dt) {
      int c = h * 64 + dt * 16 + lc;
      size_t base = ((size_t)b * 512 + c) * 1024 + n0w + rf * 16 + 4 * lg;
      float4 xr = *(const float4*)(x + base);
      float4 o;
      o.x = oacc[rf][dt][0] * inv[0] + xr.x;
      o.y = oacc[rf][dt][1] * inv[1] + xr.y;
      o.z = oacc[rf][dt][2] * inv[2] + xr.z;
      o.w = oacc[rf][dt][3] * inv[3] + xr.w;
      *(float4*)(out + base) = o;
    }
  }
}

extern "C" void kernel_launch(void* const* d_in, const int* in_sizes, int n_in,
                              void* d_out, int out_size, void* d_ws, size_t ws_size,
                              hipStream_t stream) {
  (void)in_sizes; (void)n_in; (void)out_size; (void)ws_size;
  const float* x = (const float*)d_in[0];
  const float* Wq = (const float*)d_in[1];
  const float* bq = (const float*)d_in[2];
  const float* Wk = (const float*)d_in[3];
  const float* bk = (const float*)d_in[4];
  const float* Wv = (const float*)d_in[5];
  const float* bv = (const float*)d_in[6];
  const float* rel_h = (const float*)d_in[7];
  const float* rel_w = (const float*)d_in[8];
  float* out = (float*)d_out;

  char* ws = (char*)d_ws;
  _Float16* Xt   = (_Float16*)(ws);                          // 16 MiB
  _Float16* Wall = (_Float16*)(ws + (16u << 20));            // 1.5 MiB
  _Float16* post = (_Float16*)(ws + (18u << 20));            // 1 MiB
  _Float16* Kext = (_Float16*)(ws + (19u << 20));            // 32 MiB
  _Float16* vw   = (_Float16*)(ws + (51u << 20));            // 16 MiB

  hipLaunchKernelGGL(prep_kernel, dim3(5120), dim3(256), 0, stream,
                     Wq, Wk, Wv, rel_h, rel_w, Wall, post);
  hipLaunchKernelGGL(transpose_kernel, dim3(2048), dim3(256), 0, stream, x, Xt);
  hipLaunchKernelGGL(qkv_gemm, dim3(1536), dim3(256), 0, stream,
                     Wall, Xt, bq, bk, bv, Kext, vw);
  hipLaunchKernelGGL(attn_kernel, dim3(1024), dim3(256), 0, stream,
                     Kext, vw, post, x, out);
}